// Round 19
// baseline (500.706 us; speedup 1.0000x reference)
//
#include <hip/hip_runtime.h>
#include <stdint.h>

typedef __attribute__((ext_vector_type(8))) __bf16 bf16x8;
typedef __attribute__((ext_vector_type(4))) float f32x4;

__device__ __forceinline__ f32x4 MFMA(bf16x8 a, bf16x8 b, f32x4 c) {
    return __builtin_amdgcn_mfma_f32_16x16x32_bf16(a, b, c, 0, 0, 0);
}

typedef __attribute__((address_space(1))) void gas_void;
typedef __attribute__((address_space(3))) void las_void;
__device__ __forceinline__ void gload_lds16(const __bf16* g, __bf16* l) {
    __builtin_amdgcn_global_load_lds((gas_void*)g, (las_void*)l, 16, 0, 0);
}

// ===========================================================================
// Weight convert+transpose: fp32 [OC][IC][3][3] -> PRE-SWIZZLED LDS images:
//   [z][chunk][ ((t*32 + oc)*32 + swz_q) ]  (M=32, ICB=32 for all consumers)
// swz_q = sg*8 + e with sg = (g ^ oc ^ (oc>>2)) & 3 (involution).
// OC padded to OCP (kw2: 400 -> 416) with zeros so staging needs no guard.
// ===========================================================================
struct WSeg { const float* src; int off, OC, OCP, IC; };
struct WTab { WSeg s[28]; };

__global__ __launch_bounds__(256) void wcvt_k(WTab tab, __bf16* dst, int seg0) {
    const WSeg sg = tab.s[seg0 + blockIdx.y];
    const int n = sg.OCP * sg.IC * 9;
    int d = blockIdx.x * 256 + threadIdx.x;
    if (d >= n) return;
    int q   = d & 31;
    int r1  = d >> 5;           // ((z*CH + c)*9 + t)*32 + oc
    int oc  = r1 & 31;
    int r2  = r1 >> 5;          // (z*CH + c)*9 + t
    int t   = r2 % 9;
    int r3  = r2 / 9;           // z*CH + c
    const int CH = sg.IC >> 5;
    int c   = r3 % CH;
    int z   = r3 / CH;
    int sq  = q >> 3, e = q & 7;
    int g   = (sq ^ oc ^ (oc >> 2)) & 3;      // invert involutive swizzle
    int ic  = c * 32 + g * 8 + e;
    int ocg = z * 32 + oc;
    float v = (ocg < sg.OC) ? sg.src[((size_t)ocg * sg.IC + ic) * 9 + t] : 0.f;
    dst[(size_t)sg.off + d] = (__bf16)v;
}

// ===========================================================================
// conv_in: 3->64 fp32 planar in, bf16 NHWC out: F (linear) + Fr (relu'd).
// ===========================================================================
__global__ __launch_bounds__(256) void conv_in_k(
    const float* __restrict__ x, const float* __restrict__ w,
    const float* __restrict__ bias, __bf16* __restrict__ out,
    __bf16* __restrict__ outr)
{
    const int tid = threadIdx.x;
    const int ty = (blockIdx.x >> 3) * 16, tx = (blockIdx.x & 7) * 16;
    const int b = blockIdx.y;
    __shared__ float xs[3][18][18];
    __shared__ float wl[27][64];
    for (int i = tid; i < 27 * 64; i += 256) {
        int t = i >> 6, oc = i & 63;
        wl[t][oc] = w[oc * 27 + t];
    }
    for (int i = tid; i < 3 * 324; i += 256) {
        int c = i / 324, r = i - c * 324;
        int y = r / 18, xx = r - y * 18;
        int gy = ty + y - 1, gx = tx + xx - 1;
        float v = 0.f;
        if (gy >= 0 && gy < 128 && gx >= 0 && gx < 128)
            v = x[((size_t)(b * 3 + c) * 128 + gy) * 128 + gx];
        xs[c][y][xx] = v;
    }
    __syncthreads();
    const int py = tid >> 4, px = tid & 15;
    float acc[64];
#pragma unroll
    for (int o = 0; o < 64; o++) acc[o] = bias[o];
    for (int c = 0; c < 3; c++)
        for (int t = 0; t < 9; t++) {
            float p = xs[c][py + t / 3][px + t % 3];
            const float* wr = &wl[c * 9 + t][0];
#pragma unroll
            for (int o = 0; o < 64; o++) acc[o] = fmaf(p, wr[o], acc[o]);
        }
    size_t base = (((size_t)b * 16384) + (ty + py) * 128 + (tx + px)) * 64;
    for (int o = 0; o < 64; o += 8) {
        union { bf16x8 v; uint4 u; } pk, pr;
#pragma unroll
        for (int j = 0; j < 8; j++) {
            pk.v[j] = (__bf16)acc[o + j];
            pr.v[j] = (__bf16)fmaxf(acc[o + j], 0.f);
        }
        *(uint4*)(out + base + o) = pk.u;
        *(uint4*)(outr + base + o) = pr.u;
    }
}

// ===========================================================================
// MFMA 3x3 conv. NHWC bf16 in (pre-activated); wt = PRE-SWIZZLED images.
// 16x16 px tile, 4 waves; wave = M=MT*16 oc x N=64 px (4 rows of 16).
// ALL staging zero-VALU: weights + input via gload_lds with precomputed
// chunk-invariant address tables (swizzle carried on global source addr).
// OUTM: 0 = NHWC bf16 (OCGUARD tail mask; WRELU -> extra relu'd copy to fr);
//       2 = PS2 sub-plane NHWC16 [b][sub][H][W][OCALL/4];
//       3 = PS2 FULL NHWC [b][2H][2W][OCALL/4].
// ===========================================================================
template<int CIN, int ICB, int MT, int OUTM,
         bool RELU_OUT, bool ACCUM, bool OCGUARD, bool WRELU>
__global__ __launch_bounds__(256) void convm_k(
    const __bf16* __restrict__ in, const __bf16* __restrict__ wt,
    const float* __restrict__ bias, void* __restrict__ outv,
    const __bf16* __restrict__ zp, __bf16* __restrict__ fr,
    int H, int W, int OCALL, int ocb0)
{
    constexpr int M = MT * 16;
    constexpr int CHUNKS = CIN / ICB;
    constexpr int GR = ICB / 8;
    constexpr int GM = (GR >= 8 ? 7 : GR - 1);
    constexpr int KS = ICB / 32;
    constexpr int WELEM = 9 * M * ICB;
    constexpr int WGRP = WELEM / 512;
    constexpr int NISS = (336 * ICB) / 512;

    const int tid = threadIdx.x;
    const int ntx = W >> 4;
    const int q = gridDim.x >> 3;
    const int tile = (blockIdx.x & 7) * q + (blockIdx.x >> 3);
    const int h0 = (tile / ntx) << 4;
    const int w0 = (tile % ntx) << 4;
    const int b = blockIdx.y;
    const int ocb = ocb0 + blockIdx.z * M;

    __shared__ __bf16 inT[336 * ICB];
    __shared__ __bf16 wT[WELEM];

    const int lane = tid & 63;
    const int wv = tid >> 6;
    const int cl = lane & 15;
    const int kg = lane >> 4;
    const int row0 = wv << 2;

    const __bf16* wimg = wt + (size_t)blockIdx.z * CHUNKS * WELEM;

#define SWZ(g, r) (((g) & ~GM) | (((g) ^ (r) ^ ((r) >> 2)) & GM))

    // ---- precompute chunk-invariant staging address tables (registers)
    int soff[6];
    unsigned svalid = 0;
#pragma unroll
    for (int n = 0; n < 6; n++) {
        int J = wv + n * 4;
        soff[n] = 0;
        if (J < NISS) {
            int G = J * 64 + lane;
            int pix = G >> 2, sg = G & 3;
            int y = pix / 18, xx = pix - y * 18;
            int gy = h0 + y - 1, gx = w0 + xx - 1;
            int g = SWZ(sg, pix);
            if (pix < 324 && gy >= 0 && gy < H && gx >= 0 && gx < W)
                svalid |= 1u << n;
            soff[n] = ((b * H + gy) * W + gx) * CIN + g * 8;
        }
    }

    f32x4 acc[MT][4];
#pragma unroll
    for (int m = 0; m < MT; m++) {
        f32x4 bv;
#pragma unroll
        for (int j = 0; j < 4; j++) {
            int o = ocb + m * 16 + kg * 4 + j;
            bv[j] = (!OCGUARD || o < OCALL) ? bias[o] : 0.f;
        }
#pragma unroll
        for (int n = 0; n < 4; n++) acc[m][n] = bv;
    }

    for (int c = 0; c < CHUNKS; c++) {
        if (c) __syncthreads();
        // ---- weights: direct global->LDS linear copy of pre-swizzled image
        {
            const __bf16* wsrc = wimg + (size_t)c * WELEM;
            for (int j = wv; j < WGRP; j += 4)
                gload_lds16(wsrc + (size_t)j * 512 + lane * 8,
                            wT + (size_t)j * 512);
        }
        // ---- input: direct gload with precomputed per-lane source addrs
#pragma unroll
        for (int n = 0; n < 6; n++) {
            int J = wv + n * 4;
            if (J < NISS) {
                const __bf16* src = ((svalid >> n) & 1u)
                    ? in + soff[n] + c * ICB : zp;
                gload_lds16(src, inT + (size_t)J * 512);
            }
        }
        __syncthreads();

        // ---- 9 taps x K-steps of MFMA
#pragma unroll
        for (int t = 0; t < 9; t++) {
            const int dy = t / 3, dx = t % 3;
            const __bf16* wb = wT + t * M * ICB;
#pragma unroll
            for (int ks = 0; ks < KS; ks++) {
                bf16x8 af[MT], bfr[4];
#pragma unroll
                for (int m = 0; m < MT; m++) {
                    int oc = m * 16 + cl;
                    int g = ks * 4 + kg;
                    int sg = SWZ(g, oc);
                    af[m] = *(const bf16x8*)(wb + oc * ICB + sg * 8);
                }
#pragma unroll
                for (int n = 0; n < 4; n++) {
                    int pix = (row0 + n + dy) * 18 + cl + dx;
                    int g = ks * 4 + kg;
                    int sg = SWZ(g, pix);
                    bfr[n] = *(const bf16x8*)(inT + pix * ICB + sg * 8);
                }
#pragma unroll
                for (int m = 0; m < MT; m++)
#pragma unroll
                    for (int n = 0; n < 4; n++)
                        acc[m][n] = MFMA(af[m], bfr[n], acc[m][n]);
            }
        }
    }
#undef SWZ

    // ---- epilogue. C frag: col(pixel-x)=cl, oc = m*16 + kg*4 + j
    if (OUTM == 0) {
        __bf16* outp = (__bf16*)outv;
#pragma unroll
        for (int m = 0; m < MT; m++) {
            int oc = ocb + m * 16 + kg * 4;
            if (!OCGUARD || oc < OCALL) {
#pragma unroll
                for (int n = 0; n < 4; n++) {
                    size_t idx = (((size_t)(b * H + h0 + row0 + n)) * W + (w0 + cl))
                                     * OCALL + oc;
                    __bf16* op = outp + idx;
                    f32x4 v = acc[m][n];
                    if (ACCUM) {
                        union { uint2 u; __bf16 hx[4]; } old;
                        old.u = *(const uint2*)op;
#pragma unroll
                        for (int j = 0; j < 4; j++) v[j] += (float)old.hx[j];
                    }
                    union { uint2 u; __bf16 hx[4]; } pk;
#pragma unroll
                    for (int j = 0; j < 4; j++) {
                        float f = v[j];
                        if (RELU_OUT) f = fmaxf(f, 0.f);
                        pk.hx[j] = (__bf16)f;
                    }
                    *(uint2*)op = pk.u;
                    if (WRELU) {
                        union { uint2 u; __bf16 hx[4]; } pr;
#pragma unroll
                        for (int j = 0; j < 4; j++)
                            pr.hx[j] = (__bf16)fmaxf(v[j], 0.f);
                        *(uint2*)(fr + idx) = pr.u;
                    }
                }
            }
        }
    } else if (OUTM == 2) {   // PS2 sub-plane NHWC16 [b][sub][H][W][OCALL/4]
        __bf16* outp = (__bf16*)outv;
        const int HW = H * W;
        const int CP = OCALL >> 2;
#pragma unroll
        for (int m = 0; m < MT; m++) {
            int cc = (ocb + m * 16 + kg * 4) >> 2;
#pragma unroll
            for (int n = 0; n < 4; n++) {
                int pix = (h0 + row0 + n) * W + w0 + cl;
#pragma unroll
                for (int j = 0; j < 4; j++) {
                    float f = acc[m][n][j];
                    if (RELU_OUT) f = fmaxf(f, 0.f);
                    outp[((size_t)(b * 4 + j) * HW + pix) * CP + cc] = (__bf16)f;
                }
            }
        }
    } else {   // OUTM == 3: PS2 FULL NHWC [b][2H][2W][OCALL/4]
        __bf16* outp = (__bf16*)outv;
        const int CP = OCALL >> 2;
        const int H2 = 2 * H, W2 = 2 * W;
#pragma unroll
        for (int m = 0; m < MT; m++) {
            int cc = (ocb + m * 16 + kg * 4) >> 2;
#pragma unroll
            for (int n = 0; n < 4; n++) {
                int hh = h0 + row0 + n, ww = w0 + cl;
#pragma unroll
                for (int j = 0; j < 4; j++) {
                    int a = (j >> 1) & 1, bb = j & 1;
                    float f = acc[m][n][j];
                    if (RELU_OUT) f = fmaxf(f, 0.f);
                    outp[(((size_t)(b * H2 + 2 * hh + a)) * W2 + (2 * ww + bb)) * CP + cc]
                        = (__bf16)f;
                }
            }
        }
    }
}

// ===========================================================================
// r_w3: 16->3 conv @512^2 from PS2 sub-plane NHWC16 r2 [b][4][256][256][16].
// ===========================================================================
__global__ __launch_bounds__(256) void rw3_k(
    const __bf16* __restrict__ r2p, const float* __restrict__ w,
    const float* __restrict__ bias, float* __restrict__ E)
{
    const int tid = threadIdx.x;
    const int tY = (blockIdx.x >> 4) * 16;
    const int tX = (blockIdx.x & 15) * 16;
    const int b = blockIdx.y;

    __shared__ __bf16 xs[4][18][18][16];   // [sub][y][x][ch]
    __shared__ float wl[3][9][16];
    for (int i = tid; i < 432; i += 256) {
        int oc = i / 144, r = i - oc * 144;
        int t = r >> 4, e = r & 15;
        wl[oc][t][e] = w[(oc * 16 + e) * 9 + t];
    }
    for (int i = tid; i < 4 * 18 * 36; i += 256) {
        int g = i % 36; int r = i / 36;
        int y = r % 18, sub = r / 18;
        int px = g >> 1, half = g & 1;
        int gy = tY + y - 1, gx = tX + px - 1;
        uint4 v = make_uint4(0u, 0u, 0u, 0u);
        if (gy >= 0 && gy < 256 && gx >= 0 && gx < 256)
            v = *(const uint4*)(r2p
                + (((size_t)(b * 4 + sub) << 16) + (gy << 8) + gx) * 16 + half * 8);
        *(uint4*)(&xs[sub][y][px][half * 8]) = v;
    }
    __syncthreads();

    const int hyl = tid >> 3;           // 0..31
    const int hx0 = (tid & 7) * 4;      // 0..28
    float acc[3][4];
#pragma unroll
    for (int oc = 0; oc < 3; oc++)
#pragma unroll
        for (int p = 0; p < 4; p++) acc[oc][p] = bias[oc];

#pragma unroll
    for (int dy = 0; dy < 3; dy++) {
        int hy = hyl + dy - 1;
        int ys = (hy >> 1) + 1;
        int suby = (hy & 1) << 1;
#pragma unroll
        for (int dx = 0; dx < 3; dx++) {
            const int t = dy * 3 + dx;
#pragma unroll
            for (int p = 0; p < 4; p++) {
                int hx = hx0 + p + dx - 1;
                int sub = suby | (hx & 1);
                int xsx = (hx >> 1) + 1;
                const __bf16* bp = &xs[sub][ys][xsx][0];
                bf16x8 v0 = *(const bf16x8*)bp;
                bf16x8 v1 = *(const bf16x8*)(bp + 8);
#pragma unroll
                for (int e = 0; e < 8; e++) {
                    float f0 = (float)v0[e], f1 = (float)v1[e];
                    acc[0][p] = fmaf(f0, wl[0][t][e], acc[0][p]);
                    acc[1][p] = fmaf(f0, wl[1][t][e], acc[1][p]);
                    acc[2][p] = fmaf(f0, wl[2][t][e], acc[2][p]);
                    acc[0][p] = fmaf(f1, wl[0][t][e + 8], acc[0][p]);
                    acc[1][p] = fmaf(f1, wl[1][t][e + 8], acc[1][p]);
                    acc[2][p] = fmaf(f1, wl[2][t][e + 8], acc[2][p]);
                }
            }
        }
    }
    const int HY = tY * 2 + hyl, HX = tX * 2 + hx0;
#pragma unroll
    for (int oc = 0; oc < 3; oc++) {
        float4 v = make_float4(acc[oc][0], acc[oc][1], acc[oc][2], acc[oc][3]);
        *(float4*)&E[(((size_t)(b * 3 + oc)) << 18) + HY * 512 + HX] = v;
    }
}

// ===========================================================================
// filter: normalize + dynamic 5x5 + PS4 + residual. Ut NHWC [b][16384][400].
// ===========================================================================
__global__ __launch_bounds__(256) void filter_k(
    const __bf16* __restrict__ Ut, const float* __restrict__ x,
    const float* __restrict__ E, float* __restrict__ out)
{
    const int tid = threadIdx.x;
    const int s  = tid >> 4;
    const int pl = tid & 15;
    const int b  = blockIdx.y;
    const int pix0 = blockIdx.x * 16;
    const int y  = pix0 >> 7;
    const int x0 = pix0 & 127;

    __shared__ float xp[3][5][20];
    __shared__ float vs[3][16][16];
    __shared__ __bf16 ut[16][408];

    for (int i = tid; i < 800; i += 256) {
        int px = i / 50, g = i - px * 50;
        uint4 v = *(const uint4*)(Ut + ((size_t)(b * 16384 + pix0 + px) * 400 + g * 8));
        *(uint4*)(&ut[px][g * 8]) = v;
    }
    for (int i = tid; i < 300; i += 256) {
        int c = i / 100, r = i - c * 100;
        int dy = r / 20, dx = r - dy * 20;
        int gy = y + dy - 2, gx = x0 + dx - 2;
        float v = 0.f;
        if (gy >= 0 && gy < 128 && gx >= 0 && gx < 128)
            v = x[((size_t)(b * 3 + c) * 128 + gy) * 128 + gx];
        xp[c][dy][dx] = v;
    }
    __syncthreads();

    float u[25], m = 0.f;
#pragma unroll
    for (int tap = 0; tap < 25; tap++) {
        u[tap] = (float)ut[pl][tap * 16 + s];
        m += u[tap];
    }
    m *= 0.04f;
#pragma unroll
    for (int c = 0; c < 3; c++) {
        float a = 0.f;
#pragma unroll
        for (int tap = 0; tap < 25; tap++)
            a = fmaf(xp[c][tap / 5][pl + tap % 5], u[tap] - m + 0.04f, a);
        vs[c][s][pl] = a;
    }
    __syncthreads();

    const size_t Eb = (size_t)b * 3 * 262144;
    for (int i = tid; i < 768; i += 256) {
        int c = i >> 8, r = i & 255;
        int s1 = r >> 6, cc = r & 63;
        float v = vs[c][s1 * 4 + (cc & 3)][cc >> 2];
        size_t o = Eb + (size_t)c * 262144 + (size_t)(y * 4 + s1) * 512 + x0 * 4 + cc;
        out[o] = v + E[o];
    }
}

// ===========================================================================
extern "C" void kernel_launch(void* const* d_in, const int* in_sizes, int n_in,
                              void* d_out, int out_size, void* d_ws, size_t ws_size,
                              hipStream_t stream)
{
    const float* x      = (const float*)d_in[0];
    const float* w_in   = (const float*)d_in[1];
    const float* b_in   = (const float*)d_in[2];
    const float* res_w1 = (const float*)d_in[3];
    const float* res_b1 = (const float*)d_in[4];
    const float* res_w2 = (const float*)d_in[5];
    const float* res_b2 = (const float*)d_in[6];
    const float* r_w1   = (const float*)d_in[7];
    const float* r_b1   = (const float*)d_in[8];
    const float* r_w2   = (const float*)d_in[9];
    const float* r_b2   = (const float*)d_in[10];
    const float* r_w3   = (const float*)d_in[11];
    const float* r_b3   = (const float*)d_in[12];
    const float* k_w1   = (const float*)d_in[13];
    const float* k_b1   = (const float*)d_in[14];
    const float* k_w2   = (const float*)d_in[15];
    const float* k_b2   = (const float*)d_in[16];
    float* out = (float*)d_out;

    char* ws = (char*)d_ws;
    __bf16* WT = (__bf16*)ws;                   // pre-swizzled weights, 3.06 MB
    __bf16* ZP = (__bf16*)(ws + 3110912);       // 256B zeros page
    __bf16* F  = (__bf16*)(ws + 3145728);       // [4,128,128,64]   8.4 MB
    __bf16* Hb = (__bf16*)(ws + 11534336);      // [4,128,128,64]   8.4 MB
    __bf16* R1 = (__bf16*)(ws + 19922944);      // PS2-full NHWC32 [4,256,256,32]
    __bf16* R2 = (__bf16*)(ws + 36700160);      // [4][4][256][256][16] 33.6 MB
    __bf16* K1 = (__bf16*)(ws + 70254592);      // [4,128,128,128] 16.8 MB
    float*  E  = (float*) (ws + 87031808);      // [4,3,512,512]   12.6 MB
    __bf16* Fr = (__bf16*)(ws + 99614720);      // relu'd F shadow  8.4 MB
    __bf16* Ut = (__bf16*)(ws + 3145728);       // [4][16384][400] 52.4 MB (overlay)

    const int oRes1 = 0, oRes2 = 442368, oRw1 = 884736, oKw1 = 958464,
              oRw2 = 1032192, oKw2 = 1050624;   // end 1529856 < cap

    WTab tab;
    for (int i = 0; i < 12; i++)
        tab.s[i]      = { res_w1 + (size_t)i * 36864, oRes1 + i * 36864, 64, 64, 64 };
    for (int i = 0; i < 12; i++)
        tab.s[12 + i] = { res_w2 + (size_t)i * 36864, oRes2 + i * 36864, 64, 64, 64 };
    tab.s[24] = { r_w1, oRw1, 128, 128, 64 };
    tab.s[25] = { k_w1, oKw1, 128, 128, 64 };
    tab.s[26] = { r_w2, oRw2, 64, 64, 32 };
    tab.s[27] = { k_w2, oKw2, 400, 416, 128 };

    dim3 blk(256);
    hipMemsetAsync(ZP, 0, 256, stream);
    wcvt_k<<<dim3(288, 27), blk, 0, stream>>>(tab, WT, 0);
    wcvt_k<<<dim3(1872, 1), blk, 0, stream>>>(tab, WT, 27);

    conv_in_k<<<dim3(64, 4), blk, 0, stream>>>(x, w_in, b_in, F, Fr);

    // 12 residual blocks — all STAGE-2 zero-VALU staging:
    //   conv1: Fr -> Hb (relu'd);  conv2: Hb -> F (accum) + Fr (relu'd copy)
    for (int i = 0; i < 12; i++) {
        convm_k<64, 32, 2, 0, true, false, false, false>
            <<<dim3(64, 4, 2), blk, 0, stream>>>(
            Fr, WT + oRes1 + i * 36864, res_b1 + i * 64, Hb, ZP, Fr, 128, 128, 64, 0);
        convm_k<64, 32, 2, 0, false, true, false, true>
            <<<dim3(64, 4, 2), blk, 0, stream>>>(
            Hb, WT + oRes2 + i * 36864, res_b2 + i * 64, F, ZP, Fr, 128, 128, 64, 0);
    }

    // residual branch: r_w1 (from Fr) -> R1 (PS2 FULL NHWC32, relu'd)
    convm_k<64, 32, 2, 3, true, false, false, false>
        <<<dim3(64, 4, 4), blk, 0, stream>>>(
        Fr, WT + oRw1, r_b1, R1, ZP, Fr, 128, 128, 128, 0);
    convm_k<32, 32, 2, 2, true, false, false, false>
        <<<dim3(256, 4, 2), blk, 0, stream>>>(
        R1, WT + oRw2, r_b2, R2, ZP, Fr, 256, 256, 64, 0);
    rw3_k<<<dim3(256, 4), blk, 0, stream>>>(R2, r_w3, r_b3, E);

    // kernel branch stem: k1 = relu(conv(Fr))
    convm_k<64, 32, 2, 0, true, false, false, false>
        <<<dim3(64, 4, 4), blk, 0, stream>>>(
        Fr, WT + oKw1, k_b1, K1, ZP, Fr, 128, 128, 128, 0);

    // up-kernel GEMM -> Ut NHWC [b][16384][400] (13 z-blocks of 32, guarded)
    convm_k<128, 32, 2, 0, false, false, true, false>
        <<<dim3(64, 4, 13), blk, 0, stream>>>(
        K1, WT + oKw2, k_b2, Ut, ZP, Fr, 128, 128, 400, 0);

    // normalize + dynamic filter + PS4 + residual
    filter_k<<<dim3(1024, 4), blk, 0, stream>>>(Ut, x, E, out);
}

// Round 20
// 488.146 us; speedup vs baseline: 1.0257x; 1.0257x over previous
//
#include <hip/hip_runtime.h>
#include <stdint.h>

typedef __attribute__((ext_vector_type(8))) __bf16 bf16x8;
typedef __attribute__((ext_vector_type(4))) float f32x4;

__device__ __forceinline__ f32x4 MFMA(bf16x8 a, bf16x8 b, f32x4 c) {
    return __builtin_amdgcn_mfma_f32_16x16x32_bf16(a, b, c, 0, 0, 0);
}

// Direct global->LDS 16B copy: LDS dest = wave-uniform base + lane*16,
// global source is PER-LANE (swizzle carried on the source address).
typedef __attribute__((address_space(1))) void gas_void;
typedef __attribute__((address_space(3))) void las_void;
__device__ __forceinline__ void gload_lds16(const __bf16* g, __bf16* l) {
    __builtin_amdgcn_global_load_lds((gas_void*)g, (las_void*)l, 16, 0, 0);
}

// ===========================================================================
// Weight convert+transpose: fp32 [OC][IC][3][3] -> PRE-SWIZZLED LDS images:
//   [z][chunk][ ((t*32 + oc)*32 + swz_q) ]  (M=32, ICB=32 for all consumers)
// swz_q = sg*8 + e with sg = (g ^ oc ^ (oc>>2)) & 3 (involution).
// OC padded to OCP (kw2: 400 -> 416) with zeros so staging needs no guard.
// ===========================================================================
struct WSeg { const float* src; int off, OC, OCP, IC; };
struct WTab { WSeg s[28]; };

__global__ __launch_bounds__(256) void wcvt_k(WTab tab, __bf16* dst, int seg0) {
    const WSeg sg = tab.s[seg0 + blockIdx.y];
    const int n = sg.OCP * sg.IC * 9;
    int d = blockIdx.x * 256 + threadIdx.x;
    if (d >= n) return;
    int q   = d & 31;
    int r1  = d >> 5;           // ((z*CH + c)*9 + t)*32 + oc
    int oc  = r1 & 31;
    int r2  = r1 >> 5;          // (z*CH + c)*9 + t
    int t   = r2 % 9;
    int r3  = r2 / 9;           // z*CH + c
    const int CH = sg.IC >> 5;
    int c   = r3 % CH;
    int z   = r3 / CH;
    int sq  = q >> 3, e = q & 7;
    int g   = (sq ^ oc ^ (oc >> 2)) & 3;      // invert involutive swizzle
    int ic  = c * 32 + g * 8 + e;
    int ocg = z * 32 + oc;
    float v = (ocg < sg.OC) ? sg.src[((size_t)ocg * sg.IC + ic) * 9 + t] : 0.f;
    dst[(size_t)sg.off + d] = (__bf16)v;
}

// ===========================================================================
// conv_in: 3->64 fp32 planar in, bf16 NHWC out. 16x16 tile, 1 px/thread.
// ===========================================================================
__global__ __launch_bounds__(256) void conv_in_k(
    const float* __restrict__ x, const float* __restrict__ w,
    const float* __restrict__ bias, __bf16* __restrict__ out)
{
    const int tid = threadIdx.x;
    const int ty = (blockIdx.x >> 3) * 16, tx = (blockIdx.x & 7) * 16;
    const int b = blockIdx.y;
    __shared__ float xs[3][18][18];
    __shared__ float wl[27][64];
    for (int i = tid; i < 27 * 64; i += 256) {
        int t = i >> 6, oc = i & 63;
        wl[t][oc] = w[oc * 27 + t];
    }
    for (int i = tid; i < 3 * 324; i += 256) {
        int c = i / 324, r = i - c * 324;
        int y = r / 18, xx = r - y * 18;
        int gy = ty + y - 1, gx = tx + xx - 1;
        float v = 0.f;
        if (gy >= 0 && gy < 128 && gx >= 0 && gx < 128)
            v = x[((size_t)(b * 3 + c) * 128 + gy) * 128 + gx];
        xs[c][y][xx] = v;
    }
    __syncthreads();
    const int py = tid >> 4, px = tid & 15;
    float acc[64];
#pragma unroll
    for (int o = 0; o < 64; o++) acc[o] = bias[o];
    for (int c = 0; c < 3; c++)
        for (int t = 0; t < 9; t++) {
            float p = xs[c][py + t / 3][px + t % 3];
            const float* wr = &wl[c * 9 + t][0];
#pragma unroll
            for (int o = 0; o < 64; o++) acc[o] = fmaf(p, wr[o], acc[o]);
        }
    __bf16* op = out + (((size_t)b * 16384) + (ty + py) * 128 + (tx + px)) * 64;
    for (int o = 0; o < 64; o += 8) {
        union { bf16x8 v; uint4 u; } pk;
#pragma unroll
        for (int j = 0; j < 8; j++) pk.v[j] = (__bf16)acc[o + j];
        *(uint4*)(op + o) = pk.u;
    }
}

// ===========================================================================
// MFMA 3x3 conv. NHWC bf16 in; wt = PRE-SWIZZLED segment base (wcvt layout).
// 16x16 px tile, 4 waves; wave = M=MT*16 oc x N=64 px (4 rows of 16).
// Weight staging = linear global_load_lds (zero VALU).
// Staging ADDRESSES precomputed once per block (chunk-invariant register
// tables: global offset + validity mask + LDS offset), chunk adds c*ICB.
// STAGE: 0 = VGPR-path NHWC staging (supports RELU_IN);
//        2 = direct gload_lds NHWC staging (requires RELU_IN=false).
// OUTM: 0 = NHWC bf16 (OCGUARD tail mask);
//       2 = PS2 sub-plane NHWC16 [b][sub][H][W][OCALL/4];
//       3 = PS2 FULL NHWC [b][2H][2W][OCALL/4] (plain NHWC at 2x res).
// ===========================================================================
template<int CIN, int ICB, int MT, int STAGE, int OUTM,
         bool RELU_IN, bool RELU_OUT, bool ACCUM, bool OCGUARD>
__global__ __launch_bounds__(256) void convm_k(
    const __bf16* __restrict__ in, const __bf16* __restrict__ wt,
    const float* __restrict__ bias, void* __restrict__ outv,
    const __bf16* __restrict__ zp,   // 256B zeros page (STAGE==2)
    int H, int W, int OCALL, int ocb0)
{
    constexpr int M = MT * 16;
    constexpr int CHUNKS = CIN / ICB;
    constexpr int GR = ICB / 8;               // 16B groups per row
    constexpr int GM = (GR >= 8 ? 7 : GR - 1);
    constexpr int KS = ICB / 32;
    constexpr int WELEM = 9 * M * ICB;        // elems per chunk weight image
    constexpr int WGRP = WELEM / 512;         // 64-lane x 16B groups
    constexpr int NISS = (336 * ICB) / 512;   // input gload issues (pad 324->336)

    const int tid = threadIdx.x;
    const int ntx = W >> 4;
    // XCD-aware swizzle: co-resident blocks on one XCD get consecutive tiles
    const int q = gridDim.x >> 3;
    const int tile = (blockIdx.x & 7) * q + (blockIdx.x >> 3);
    const int h0 = (tile / ntx) << 4;
    const int w0 = (tile % ntx) << 4;
    const int b = blockIdx.y;
    const int ocb = ocb0 + blockIdx.z * M;

    __shared__ __bf16 inT[336 * ICB];         // 324 used, 12 px padding
    __shared__ __bf16 wT[WELEM];

    const int lane = tid & 63;
    const int wv = tid >> 6;
    const int cl = lane & 15;     // col (pixel-x / oc-low for A rows)
    const int kg = lane >> 4;     // k-group
    const int row0 = wv << 2;

    const __bf16* wimg = wt + (size_t)blockIdx.z * CHUNKS * WELEM;

#define SWZ(g, r) (((g) & ~GM) | (((g) ^ (r) ^ ((r) >> 2)) & GM))

    // ---- precompute chunk-invariant staging address tables (registers)
    int soff[6];
    int slds[6];
    unsigned svalid = 0;
    if (STAGE == 0) {
#pragma unroll
        for (int n = 0; n < 6; n++) {
            int i = tid + n * 256;
            soff[n] = 0; slds[n] = 336 * ICB - 8;   // safe defaults
            if (i < 324 * GR) {
                int pix = i / GR, g = i - pix * GR;
                int y = pix / 18, xx = pix - y * 18;
                int gy = h0 + y - 1, gx = w0 + xx - 1;
                if (gy >= 0 && gy < H && gx >= 0 && gx < W) svalid |= 1u << n;
                soff[n] = ((b * H + gy) * W + gx) * CIN + g * 8;
                slds[n] = pix * ICB + SWZ(g, pix) * 8;
            }
        }
    } else {
#pragma unroll
        for (int n = 0; n < 6; n++) {
            int J = wv + n * 4;
            soff[n] = 0;
            if (J < NISS) {
                int G = J * 64 + lane;
                int pix = G >> 2, sg = G & 3;
                int y = pix / 18, xx = pix - y * 18;
                int gy = h0 + y - 1, gx = w0 + xx - 1;
                int g = SWZ(sg, pix);
                if (pix < 324 && gy >= 0 && gy < H && gx >= 0 && gx < W)
                    svalid |= 1u << n;
                soff[n] = ((b * H + gy) * W + gx) * CIN + g * 8;
            }
        }
    }

    f32x4 acc[MT][4];
#pragma unroll
    for (int m = 0; m < MT; m++) {
        f32x4 bv;
#pragma unroll
        for (int j = 0; j < 4; j++) {
            int o = ocb + m * 16 + kg * 4 + j;
            bv[j] = (!OCGUARD || o < OCALL) ? bias[o] : 0.f;
        }
#pragma unroll
        for (int n = 0; n < 4; n++) acc[m][n] = bv;
    }

    for (int c = 0; c < CHUNKS; c++) {
        if (c) __syncthreads();
        // ---- weights: direct global->LDS linear copy of pre-swizzled image
        {
            const __bf16* wsrc = wimg + (size_t)c * WELEM;
            for (int j = wv; j < WGRP; j += 4)
                gload_lds16(wsrc + (size_t)j * 512 + lane * 8,
                            wT + (size_t)j * 512);
        }
        // ---- stage input halo tile (18x18) for this ic chunk
        if (STAGE == 0) {
#pragma unroll
            for (int n = 0; n < 6; n++) {
                int i = tid + n * 256;
                if (i < 324 * GR) {
                    union { uint4 u; bf16x8 v; unsigned short us[8]; } d;
                    d.u = make_uint4(0u, 0u, 0u, 0u);
                    if ((svalid >> n) & 1u) {
                        d.u = *(const uint4*)(in + soff[n] + c * ICB);
                        if (RELU_IN) {
#pragma unroll
                            for (int j = 0; j < 8; j++)
                                if (d.us[j] & 0x8000u) d.us[j] = 0;
                        }
                    }
                    *(bf16x8*)(inT + slds[n]) = d.v;
                }
            }
        } else {   // STAGE == 2
#pragma unroll
            for (int n = 0; n < 6; n++) {
                int J = wv + n * 4;
                if (J < NISS) {
                    const __bf16* src = ((svalid >> n) & 1u)
                        ? in + soff[n] + c * ICB : zp;
                    gload_lds16(src, inT + (size_t)J * 512);
                }
            }
        }
        __syncthreads();

        // ---- 9 taps x K-steps of MFMA
#pragma unroll
        for (int t = 0; t < 9; t++) {
            const int dy = t / 3, dx = t % 3;
            const __bf16* wb = wT + t * M * ICB;
#pragma unroll
            for (int ks = 0; ks < KS; ks++) {
                bf16x8 af[MT], bfr[4];
#pragma unroll
                for (int m = 0; m < MT; m++) {
                    int oc = m * 16 + cl;
                    int g = ks * 4 + kg;
                    int sg = SWZ(g, oc);
                    af[m] = *(const bf16x8*)(wb + oc * ICB + sg * 8);
                }
#pragma unroll
                for (int n = 0; n < 4; n++) {
                    int pix = (row0 + n + dy) * 18 + cl + dx;
                    int g = ks * 4 + kg;
                    int sg = SWZ(g, pix);
                    bfr[n] = *(const bf16x8*)(inT + pix * ICB + sg * 8);
                }
#pragma unroll
                for (int m = 0; m < MT; m++)
#pragma unroll
                    for (int n = 0; n < 4; n++)
                        acc[m][n] = MFMA(af[m], bfr[n], acc[m][n]);
            }
        }
    }
#undef SWZ

    // ---- epilogue. C frag: col(pixel-x)=cl, oc = m*16 + kg*4 + j
    if (OUTM == 0) {
        __bf16* outp = (__bf16*)outv;
#pragma unroll
        for (int m = 0; m < MT; m++) {
            int oc = ocb + m * 16 + kg * 4;
            if (!OCGUARD || oc < OCALL) {
#pragma unroll
                for (int n = 0; n < 4; n++) {
                    __bf16* op = outp + (((size_t)(b * H + h0 + row0 + n)) * W + (w0 + cl))
                                     * OCALL + oc;
                    f32x4 v = acc[m][n];
                    if (ACCUM) {
                        union { uint2 u; __bf16 hx[4]; } old;
                        old.u = *(const uint2*)op;
#pragma unroll
                        for (int j = 0; j < 4; j++) v[j] += (float)old.hx[j];
                    }
                    union { uint2 u; __bf16 hx[4]; } pk;
#pragma unroll
                    for (int j = 0; j < 4; j++) {
                        float f = v[j];
                        if (RELU_OUT) f = fmaxf(f, 0.f);
                        pk.hx[j] = (__bf16)f;
                    }
                    *(uint2*)op = pk.u;
                }
            }
        }
    } else if (OUTM == 2) {   // PS2 sub-plane NHWC16 [b][sub][H][W][OCALL/4]
        __bf16* outp = (__bf16*)outv;
        const int HW = H * W;
        const int CP = OCALL >> 2;
#pragma unroll
        for (int m = 0; m < MT; m++) {
            int cc = (ocb + m * 16 + kg * 4) >> 2;   // channel in sub-plane
#pragma unroll
            for (int n = 0; n < 4; n++) {
                int pix = (h0 + row0 + n) * W + w0 + cl;
#pragma unroll
                for (int j = 0; j < 4; j++) {        // j == subpixel index
                    float f = acc[m][n][j];
                    if (RELU_OUT) f = fmaxf(f, 0.f);
                    outp[((size_t)(b * 4 + j) * HW + pix) * CP + cc] = (__bf16)f;
                }
            }
        }
    } else {   // OUTM == 3: PS2 FULL NHWC [b][2H][2W][OCALL/4]
        __bf16* outp = (__bf16*)outv;
        const int CP = OCALL >> 2;
        const int H2 = 2 * H, W2 = 2 * W;
#pragma unroll
        for (int m = 0; m < MT; m++) {
            int cc = (ocb + m * 16 + kg * 4) >> 2;
#pragma unroll
            for (int n = 0; n < 4; n++) {
                int hh = h0 + row0 + n, ww = w0 + cl;
#pragma unroll
                for (int j = 0; j < 4; j++) {
                    // oc = cc*4 + a*2 + bb -> HR pixel (2h+a, 2w+bb)
                    int a = (j >> 1) & 1, bb = j & 1;
                    float f = acc[m][n][j];
                    if (RELU_OUT) f = fmaxf(f, 0.f);
                    outp[(((size_t)(b * H2 + 2 * hh + a)) * W2 + (2 * ww + bb)) * CP + cc]
                        = (__bf16)f;
                }
            }
        }
    }
}

// ===========================================================================
// r_w3: 16->3 conv @512^2 from PS2 sub-plane NHWC16 r2 [b][4][256][256][16].
// ===========================================================================
__global__ __launch_bounds__(256) void rw3_k(
    const __bf16* __restrict__ r2p, const float* __restrict__ w,
    const float* __restrict__ bias, float* __restrict__ E)
{
    const int tid = threadIdx.x;
    const int tY = (blockIdx.x >> 4) * 16;
    const int tX = (blockIdx.x & 15) * 16;
    const int b = blockIdx.y;

    __shared__ __bf16 xs[4][18][18][16];   // [sub][y][x][ch]
    __shared__ float wl[3][9][16];
    for (int i = tid; i < 432; i += 256) {
        int oc = i / 144, r = i - oc * 144;
        int t = r >> 4, e = r & 15;
        wl[oc][t][e] = w[(oc * 16 + e) * 9 + t];
    }
    for (int i = tid; i < 4 * 18 * 36; i += 256) {
        int g = i % 36; int r = i / 36;
        int y = r % 18, sub = r / 18;
        int px = g >> 1, half = g & 1;
        int gy = tY + y - 1, gx = tX + px - 1;
        uint4 v = make_uint4(0u, 0u, 0u, 0u);
        if (gy >= 0 && gy < 256 && gx >= 0 && gx < 256)
            v = *(const uint4*)(r2p
                + (((size_t)(b * 4 + sub) << 16) + (gy << 8) + gx) * 16 + half * 8);
        *(uint4*)(&xs[sub][y][px][half * 8]) = v;
    }
    __syncthreads();

    const int hyl = tid >> 3;           // 0..31
    const int hx0 = (tid & 7) * 4;      // 0..28
    float acc[3][4];
#pragma unroll
    for (int oc = 0; oc < 3; oc++)
#pragma unroll
        for (int p = 0; p < 4; p++) acc[oc][p] = bias[oc];

#pragma unroll
    for (int dy = 0; dy < 3; dy++) {
        int hy = hyl + dy - 1;
        int ys = (hy >> 1) + 1;
        int suby = (hy & 1) << 1;
#pragma unroll
        for (int dx = 0; dx < 3; dx++) {
            const int t = dy * 3 + dx;
#pragma unroll
            for (int p = 0; p < 4; p++) {
                int hx = hx0 + p + dx - 1;
                int sub = suby | (hx & 1);
                int xsx = (hx >> 1) + 1;
                const __bf16* bp = &xs[sub][ys][xsx][0];
                bf16x8 v0 = *(const bf16x8*)bp;
                bf16x8 v1 = *(const bf16x8*)(bp + 8);
#pragma unroll
                for (int e = 0; e < 8; e++) {
                    float f0 = (float)v0[e], f1 = (float)v1[e];
                    acc[0][p] = fmaf(f0, wl[0][t][e], acc[0][p]);
                    acc[1][p] = fmaf(f0, wl[1][t][e], acc[1][p]);
                    acc[2][p] = fmaf(f0, wl[2][t][e], acc[2][p]);
                    acc[0][p] = fmaf(f1, wl[0][t][e + 8], acc[0][p]);
                    acc[1][p] = fmaf(f1, wl[1][t][e + 8], acc[1][p]);
                    acc[2][p] = fmaf(f1, wl[2][t][e + 8], acc[2][p]);
                }
            }
        }
    }
    const int HY = tY * 2 + hyl, HX = tX * 2 + hx0;
#pragma unroll
    for (int oc = 0; oc < 3; oc++) {
        float4 v = make_float4(acc[oc][0], acc[oc][1], acc[oc][2], acc[oc][3]);
        *(float4*)&E[(((size_t)(b * 3 + oc)) << 18) + HY * 512 + HX] = v;
    }
}

// ===========================================================================
// filter: normalize + dynamic 5x5 + PS4 + residual. Ut NHWC [b][16384][400].
// ===========================================================================
__global__ __launch_bounds__(256) void filter_k(
    const __bf16* __restrict__ Ut, const float* __restrict__ x,
    const float* __restrict__ E, float* __restrict__ out)
{
    const int tid = threadIdx.x;
    const int s  = tid >> 4;    // subpixel 0..15
    const int pl = tid & 15;    // pixel lane
    const int b  = blockIdx.y;
    const int pix0 = blockIdx.x * 16;
    const int y  = pix0 >> 7;
    const int x0 = pix0 & 127;

    __shared__ float xp[3][5][20];
    __shared__ float vs[3][16][16];    // [c][s][pl]
    __shared__ __bf16 ut[16][408];     // [px][ch], padded row

    for (int i = tid; i < 800; i += 256) {         // 16 px x 50 groups of 8
        int px = i / 50, g = i - px * 50;
        uint4 v = *(const uint4*)(Ut + ((size_t)(b * 16384 + pix0 + px) * 400 + g * 8));
        *(uint4*)(&ut[px][g * 8]) = v;
    }
    for (int i = tid; i < 300; i += 256) {
        int c = i / 100, r = i - c * 100;
        int dy = r / 20, dx = r - dy * 20;
        int gy = y + dy - 2, gx = x0 + dx - 2;
        float v = 0.f;
        if (gy >= 0 && gy < 128 && gx >= 0 && gx < 128)
            v = x[((size_t)(b * 3 + c) * 128 + gy) * 128 + gx];
        xp[c][dy][dx] = v;
    }
    __syncthreads();

    float u[25], m = 0.f;
#pragma unroll
    for (int tap = 0; tap < 25; tap++) {
        u[tap] = (float)ut[pl][tap * 16 + s];
        m += u[tap];
    }
    m *= 0.04f;
#pragma unroll
    for (int c = 0; c < 3; c++) {
        float a = 0.f;
#pragma unroll
        for (int tap = 0; tap < 25; tap++)
            a = fmaf(xp[c][tap / 5][pl + tap % 5], u[tap] - m + 0.04f, a);
        vs[c][s][pl] = a;
    }
    __syncthreads();

    const size_t Eb = (size_t)b * 3 * 262144;
    for (int i = tid; i < 768; i += 256) {
        int c = i >> 8, r = i & 255;
        int s1 = r >> 6, cc = r & 63;
        float v = vs[c][s1 * 4 + (cc & 3)][cc >> 2];
        size_t o = Eb + (size_t)c * 262144 + (size_t)(y * 4 + s1) * 512 + x0 * 4 + cc;
        out[o] = v + E[o];
    }
}

// ===========================================================================
extern "C" void kernel_launch(void* const* d_in, const int* in_sizes, int n_in,
                              void* d_out, int out_size, void* d_ws, size_t ws_size,
                              hipStream_t stream)
{
    const float* x      = (const float*)d_in[0];
    const float* w_in   = (const float*)d_in[1];
    const float* b_in   = (const float*)d_in[2];
    const float* res_w1 = (const float*)d_in[3];
    const float* res_b1 = (const float*)d_in[4];
    const float* res_w2 = (const float*)d_in[5];
    const float* res_b2 = (const float*)d_in[6];
    const float* r_w1   = (const float*)d_in[7];
    const float* r_b1   = (const float*)d_in[8];
    const float* r_w2   = (const float*)d_in[9];
    const float* r_b2   = (const float*)d_in[10];
    const float* r_w3   = (const float*)d_in[11];
    const float* r_b3   = (const float*)d_in[12];
    const float* k_w1   = (const float*)d_in[13];
    const float* k_b1   = (const float*)d_in[14];
    const float* k_w2   = (const float*)d_in[15];
    const float* k_b2   = (const float*)d_in[16];
    float* out = (float*)d_out;

    char* ws = (char*)d_ws;
    __bf16* WT = (__bf16*)ws;                   // pre-swizzled weights, 3.06 MB
    __bf16* ZP = (__bf16*)(ws + 3110912);       // 256B zeros page
    __bf16* F  = (__bf16*)(ws + 3145728);       // [4,128,128,64]   8.4 MB
    __bf16* Hb = (__bf16*)(ws + 11534336);      // [4,128,128,64]   8.4 MB
    __bf16* R1 = (__bf16*)(ws + 19922944);      // PS2-full NHWC32 [4,256,256,32]
    __bf16* R2 = (__bf16*)(ws + 36700160);      // [4][4][256][256][16] 33.6 MB
    __bf16* K1 = (__bf16*)(ws + 70254592);      // [4,128,128,128] 16.8 MB
    float*  E  = (float*) (ws + 87031808);      // [4,3,512,512]   12.6 MB
    __bf16* Ut = (__bf16*)(ws + 3145728);       // [4][16384][400] 52.4 MB (overlay)

    // WT offsets (bf16 elems); kw2 padded to 416 ocs = 479232 elems
    const int oRes1 = 0, oRes2 = 442368, oRw1 = 884736, oKw1 = 958464,
              oRw2 = 1032192, oKw2 = 1050624;   // end 1529856 < cap

    WTab tab;
    for (int i = 0; i < 12; i++)
        tab.s[i]      = { res_w1 + (size_t)i * 36864, oRes1 + i * 36864, 64, 64, 64 };
    for (int i = 0; i < 12; i++)
        tab.s[12 + i] = { res_w2 + (size_t)i * 36864, oRes2 + i * 36864, 64, 64, 64 };
    tab.s[24] = { r_w1, oRw1, 128, 128, 64 };
    tab.s[25] = { k_w1, oKw1, 128, 128, 64 };
    tab.s[26] = { r_w2, oRw2, 64, 64, 32 };
    tab.s[27] = { k_w2, oKw2, 400, 416, 128 };

    dim3 blk(256);
    hipMemsetAsync(ZP, 0, 256, stream);
    // 288 blocks covers segs 0..26 (max n = 128*64*9 = 73728 = 288*256)
    wcvt_k<<<dim3(288, 27), blk, 0, stream>>>(tab, WT, 0);
    // kw2 padded: 416*128*9 = 479232 = 1872*256
    wcvt_k<<<dim3(1872, 1), blk, 0, stream>>>(tab, WT, 27);

    conv_in_k<<<dim3(64, 4), blk, 0, stream>>>(x, w_in, b_in, F);

    // 12 residual blocks (MT=2, ICB=32 -> ~39 KB LDS -> 4 blocks/CU)
    for (int i = 0; i < 12; i++) {
        convm_k<64, 32, 2, 0, 0, true, true, false, false>
            <<<dim3(64, 4, 2), blk, 0, stream>>>(
            F, WT + oRes1 + i * 36864, res_b1 + i * 64, Hb, ZP, 128, 128, 64, 0);
        convm_k<64, 32, 2, 2, 0, false, false, true, false>
            <<<dim3(64, 4, 2), blk, 0, stream>>>(
            Hb, WT + oRes2 + i * 36864, res_b2 + i * 64, F, ZP, 128, 128, 64, 0);
    }

    // residual branch: r_w1 -> R1 (PS2 FULL NHWC32 @256^2, ReLU'd)
    convm_k<64, 32, 2, 0, 3, true, true, false, false>
        <<<dim3(64, 4, 4), blk, 0, stream>>>(
        F, WT + oRw1, r_b1, R1, ZP, 128, 128, 128, 0);
    // r_w2: plain NHWC32 conv @256^2, zero-VALU STAGE-2 staging
    convm_k<32, 32, 2, 2, 2, false, true, false, false>
        <<<dim3(256, 4, 2), blk, 0, stream>>>(
        R1, WT + oRw2, r_b2, R2, ZP, 256, 256, 64, 0);
    rw3_k<<<dim3(256, 4), blk, 0, stream>>>(R2, r_w3, r_b3, E);

    // kernel branch stem: k1 = relu(conv(relu(f)))
    convm_k<64, 32, 2, 0, 0, true, true, false, false>
        <<<dim3(64, 4, 4), blk, 0, stream>>>(
        F, WT + oKw1, k_b1, K1, ZP, 128, 128, 128, 0);

    // up-kernel GEMM -> Ut NHWC [b][16384][400] (13 z-blocks of 32, guarded)
    convm_k<128, 32, 2, 2, 0, false, false, false, true>
        <<<dim3(64, 4, 13), blk, 0, stream>>>(
        K1, WT + oKw2, k_b2, Ut, ZP, 128, 128, 400, 0);

    // normalize + dynamic filter + PS4 + residual
    filter_k<<<dim3(1024, 4), blk, 0, stream>>>(Ut, x, E, out);
}

// Round 21
// 480.536 us; speedup vs baseline: 1.0420x; 1.0158x over previous
//
#include <hip/hip_runtime.h>
#include <stdint.h>

typedef __attribute__((ext_vector_type(8))) __bf16 bf16x8;
typedef __attribute__((ext_vector_type(4))) float f32x4;

__device__ __forceinline__ f32x4 MFMA(bf16x8 a, bf16x8 b, f32x4 c) {
    return __builtin_amdgcn_mfma_f32_16x16x32_bf16(a, b, c, 0, 0, 0);
}

// Direct global->LDS 16B copy: LDS dest = wave-uniform base + lane*16,
// global source is PER-LANE (swizzle carried on the source address).
typedef __attribute__((address_space(1))) void gas_void;
typedef __attribute__((address_space(3))) void las_void;
__device__ __forceinline__ void gload_lds16(const __bf16* g, __bf16* l) {
    __builtin_amdgcn_global_load_lds((gas_void*)g, (las_void*)l, 16, 0, 0);
}

// ===========================================================================
// Weight convert+transpose: fp32 [OC][IC][3][3] -> PRE-SWIZZLED LDS images:
//   [z][c2][t][oc(32)][q(ICB)]  with q = sq*8+e, logical k-group
//   g = (sq & ~GM) | ((sq ^ oc ^ (oc>>2)) & GM)  (involution), GM=GR-1|7.
// Per-segment ICB (res/stems use 64, r_w2/kw2 use 32).
// OC padded to OCP (kw2: 400 -> 416) with zeros so staging needs no guard.
// ===========================================================================
struct WSeg { const float* src; int off, OC, OCP, IC, ICB; };
struct WTab { WSeg s[28]; };

__global__ __launch_bounds__(256) void wcvt_k(WTab tab, __bf16* dst, int seg0) {
    const WSeg sg = tab.s[seg0 + blockIdx.y];
    const int n = sg.OCP * sg.IC * 9;
    int d = blockIdx.x * 256 + threadIdx.x;
    if (d >= n) return;
    const int ICB = sg.ICB;
    const int GR = ICB >> 3;
    const int GM = (GR >= 8) ? 7 : (GR - 1);
    int q   = d % ICB;
    int r1  = d / ICB;          // ((z*CH2 + c2)*9 + t)*32 + oc
    int oc  = r1 & 31;
    int r2  = r1 >> 5;          // (z*CH2 + c2)*9 + t
    int t   = r2 % 9;
    int r3  = r2 / 9;           // z*CH2 + c2
    const int CH2 = sg.IC / ICB;
    int c2  = r3 % CH2;
    int z   = r3 / CH2;
    int sq  = q >> 3, e = q & 7;
    int g   = (sq & ~GM) | ((sq ^ oc ^ (oc >> 2)) & GM);  // invert involution
    int ic  = c2 * ICB + g * 8 + e;
    int ocg = z * 32 + oc;
    float v = (ocg < sg.OC) ? sg.src[((size_t)ocg * sg.IC + ic) * 9 + t] : 0.f;
    dst[(size_t)sg.off + d] = (__bf16)v;
}

// ===========================================================================
// conv_in: 3->64 fp32 planar in, bf16 NHWC out. 16x16 tile, 1 px/thread.
// ===========================================================================
__global__ __launch_bounds__(256) void conv_in_k(
    const float* __restrict__ x, const float* __restrict__ w,
    const float* __restrict__ bias, __bf16* __restrict__ out)
{
    const int tid = threadIdx.x;
    const int ty = (blockIdx.x >> 3) * 16, tx = (blockIdx.x & 7) * 16;
    const int b = blockIdx.y;
    __shared__ float xs[3][18][18];
    __shared__ float wl[27][64];
    for (int i = tid; i < 27 * 64; i += 256) {
        int t = i >> 6, oc = i & 63;
        wl[t][oc] = w[oc * 27 + t];
    }
    for (int i = tid; i < 3 * 324; i += 256) {
        int c = i / 324, r = i - c * 324;
        int y = r / 18, xx = r - y * 18;
        int gy = ty + y - 1, gx = tx + xx - 1;
        float v = 0.f;
        if (gy >= 0 && gy < 128 && gx >= 0 && gx < 128)
            v = x[((size_t)(b * 3 + c) * 128 + gy) * 128 + gx];
        xs[c][y][xx] = v;
    }
    __syncthreads();
    const int py = tid >> 4, px = tid & 15;
    float acc[64];
#pragma unroll
    for (int o = 0; o < 64; o++) acc[o] = bias[o];
    for (int c = 0; c < 3; c++)
        for (int t = 0; t < 9; t++) {
            float p = xs[c][py + t / 3][px + t % 3];
            const float* wr = &wl[c * 9 + t][0];
#pragma unroll
            for (int o = 0; o < 64; o++) acc[o] = fmaf(p, wr[o], acc[o]);
        }
    __bf16* op = out + (((size_t)b * 16384) + (ty + py) * 128 + (tx + px)) * 64;
    for (int o = 0; o < 64; o += 8) {
        union { bf16x8 v; uint4 u; } pk;
#pragma unroll
        for (int j = 0; j < 8; j++) pk.v[j] = (__bf16)acc[o + j];
        *(uint4*)(op + o) = pk.u;
    }
}

// ===========================================================================
// MFMA 3x3 conv. NHWC bf16 in; wt = PRE-SWIZZLED segment base (wcvt layout).
// 16x16 px tile, 4 waves; wave = M=MT*16 oc x N=64 px (4 rows of 16).
// Weight staging = linear global_load_lds (zero VALU).
// Staging ADDRESSES precomputed once per block (chunk-invariant register
// tables: global offset + validity mask + LDS offset), chunk adds c*ICB.
// ICB=64 -> single chunk: one staging burst + one barrier pair per block.
// STAGE: 0 = VGPR-path NHWC staging (supports RELU_IN);
//        2 = direct gload_lds NHWC staging (requires RELU_IN=false).
// OUTM: 0 = NHWC bf16 (OCGUARD tail mask);
//       2 = PS2 sub-plane NHWC16 [b][sub][H][W][OCALL/4];
//       3 = PS2 FULL NHWC [b][2H][2W][OCALL/4] (plain NHWC at 2x res).
// ===========================================================================
template<int CIN, int ICB, int MT, int STAGE, int OUTM,
         bool RELU_IN, bool RELU_OUT, bool ACCUM, bool OCGUARD>
__global__ __launch_bounds__(256) void convm_k(
    const __bf16* __restrict__ in, const __bf16* __restrict__ wt,
    const float* __restrict__ bias, void* __restrict__ outv,
    const __bf16* __restrict__ zp,   // 256B zeros page (STAGE==2)
    int H, int W, int OCALL, int ocb0)
{
    constexpr int M = MT * 16;
    constexpr int CHUNKS = CIN / ICB;
    constexpr int GR = ICB / 8;               // 16B groups per row
    constexpr int GM = (GR >= 8 ? 7 : GR - 1);
    constexpr int KS = ICB / 32;
    constexpr int WELEM = 9 * M * ICB;        // elems per chunk weight image
    constexpr int WGRP = WELEM / 512;         // 64-lane x 16B groups
    constexpr int NISS = (336 * ICB) / 512;   // input gload issues (pad 324->336)
    constexpr int NTAB = (STAGE == 0) ? (324 * GR + 255) / 256
                                      : (NISS + 3) / 4;

    const int tid = threadIdx.x;
    const int ntx = W >> 4;
    // XCD-aware swizzle: co-resident blocks on one XCD get consecutive tiles
    const int q = gridDim.x >> 3;
    const int tile = (blockIdx.x & 7) * q + (blockIdx.x >> 3);
    const int h0 = (tile / ntx) << 4;
    const int w0 = (tile % ntx) << 4;
    const int b = blockIdx.y;
    const int ocb = ocb0 + blockIdx.z * M;

    __shared__ __bf16 inT[336 * ICB];         // 324 used, 12 px padding
    __shared__ __bf16 wT[WELEM];

    const int lane = tid & 63;
    const int wv = tid >> 6;
    const int cl = lane & 15;     // col (pixel-x / oc-low for A rows)
    const int kg = lane >> 4;     // k-group
    const int row0 = wv << 2;

    const __bf16* wimg = wt + (size_t)blockIdx.z * CHUNKS * WELEM;

#define SWZ(g, r) (((g) & ~GM) | (((g) ^ (r) ^ ((r) >> 2)) & GM))

    // ---- precompute chunk-invariant staging address tables (registers)
    int soff[NTAB];
    int slds[NTAB];
    unsigned svalid = 0;
    if (STAGE == 0) {
#pragma unroll
        for (int n = 0; n < NTAB; n++) {
            int i = tid + n * 256;
            soff[n] = 0; slds[n] = 336 * ICB - 8;   // safe defaults
            if (i < 324 * GR) {
                int pix = i / GR, g = i - pix * GR;
                int y = pix / 18, xx = pix - y * 18;
                int gy = h0 + y - 1, gx = w0 + xx - 1;
                if (gy >= 0 && gy < H && gx >= 0 && gx < W) svalid |= 1u << n;
                soff[n] = ((b * H + gy) * W + gx) * CIN + g * 8;
                slds[n] = pix * ICB + SWZ(g, pix) * 8;
            }
        }
    } else {
#pragma unroll
        for (int n = 0; n < NTAB; n++) {
            int J = wv + n * 4;
            soff[n] = 0;
            if (J < NISS) {
                int G = J * 64 + lane;
                int pix = G / GR, sg = G - pix * GR;
                int y = pix / 18, xx = pix - y * 18;
                int gy = h0 + y - 1, gx = w0 + xx - 1;
                int g = SWZ(sg, pix);
                if (pix < 324 && gy >= 0 && gy < H && gx >= 0 && gx < W)
                    svalid |= 1u << n;
                soff[n] = ((b * H + gy) * W + gx) * CIN + g * 8;
            }
        }
    }

    f32x4 acc[MT][4];
#pragma unroll
    for (int m = 0; m < MT; m++) {
        f32x4 bv;
#pragma unroll
        for (int j = 0; j < 4; j++) {
            int o = ocb + m * 16 + kg * 4 + j;
            bv[j] = (!OCGUARD || o < OCALL) ? bias[o] : 0.f;
        }
#pragma unroll
        for (int n = 0; n < 4; n++) acc[m][n] = bv;
    }

    for (int c = 0; c < CHUNKS; c++) {
        if (c) __syncthreads();
        // ---- weights: direct global->LDS linear copy of pre-swizzled image
        {
            const __bf16* wsrc = wimg + (size_t)c * WELEM;
            for (int j = wv; j < WGRP; j += 4)
                gload_lds16(wsrc + (size_t)j * 512 + lane * 8,
                            wT + (size_t)j * 512);
        }
        // ---- stage input halo tile (18x18) for this ic chunk
        if (STAGE == 0) {
#pragma unroll
            for (int n = 0; n < NTAB; n++) {
                int i = tid + n * 256;
                if (i < 324 * GR) {
                    union { uint4 u; bf16x8 v; unsigned short us[8]; } d;
                    d.u = make_uint4(0u, 0u, 0u, 0u);
                    if ((svalid >> n) & 1u) {
                        d.u = *(const uint4*)(in + soff[n] + c * ICB);
                        if (RELU_IN) {
#pragma unroll
                            for (int j = 0; j < 8; j++)
                                if (d.us[j] & 0x8000u) d.us[j] = 0;
                        }
                    }
                    *(bf16x8*)(inT + slds[n]) = d.v;
                }
            }
        } else {   // STAGE == 2
#pragma unroll
            for (int n = 0; n < NTAB; n++) {
                int J = wv + n * 4;
                if (J < NISS) {
                    const __bf16* src = ((svalid >> n) & 1u)
                        ? in + soff[n] + c * ICB : zp;
                    gload_lds16(src, inT + (size_t)J * 512);
                }
            }
        }
        __syncthreads();

        // ---- 9 taps x K-steps of MFMA
#pragma unroll
        for (int t = 0; t < 9; t++) {
            const int dy = t / 3, dx = t % 3;
            const __bf16* wb = wT + t * M * ICB;
#pragma unroll
            for (int ks = 0; ks < KS; ks++) {
                bf16x8 af[MT], bfr[4];
#pragma unroll
                for (int m = 0; m < MT; m++) {
                    int oc = m * 16 + cl;
                    int g = ks * 4 + kg;
                    int sg = SWZ(g, oc);
                    af[m] = *(const bf16x8*)(wb + oc * ICB + sg * 8);
                }
#pragma unroll
                for (int n = 0; n < 4; n++) {
                    int pix = (row0 + n + dy) * 18 + cl + dx;
                    int g = ks * 4 + kg;
                    int sg = SWZ(g, pix);
                    bfr[n] = *(const bf16x8*)(inT + pix * ICB + sg * 8);
                }
#pragma unroll
                for (int m = 0; m < MT; m++)
#pragma unroll
                    for (int n = 0; n < 4; n++)
                        acc[m][n] = MFMA(af[m], bfr[n], acc[m][n]);
            }
        }
    }
#undef SWZ

    // ---- epilogue. C frag: col(pixel-x)=cl, oc = m*16 + kg*4 + j
    if (OUTM == 0) {
        __bf16* outp = (__bf16*)outv;
#pragma unroll
        for (int m = 0; m < MT; m++) {
            int oc = ocb + m * 16 + kg * 4;
            if (!OCGUARD || oc < OCALL) {
#pragma unroll
                for (int n = 0; n < 4; n++) {
                    __bf16* op = outp + (((size_t)(b * H + h0 + row0 + n)) * W + (w0 + cl))
                                     * OCALL + oc;
                    f32x4 v = acc[m][n];
                    if (ACCUM) {
                        union { uint2 u; __bf16 hx[4]; } old;
                        old.u = *(const uint2*)op;
#pragma unroll
                        for (int j = 0; j < 4; j++) v[j] += (float)old.hx[j];
                    }
                    union { uint2 u; __bf16 hx[4]; } pk;
#pragma unroll
                    for (int j = 0; j < 4; j++) {
                        float f = v[j];
                        if (RELU_OUT) f = fmaxf(f, 0.f);
                        pk.hx[j] = (__bf16)f;
                    }
                    *(uint2*)op = pk.u;
                }
            }
        }
    } else if (OUTM == 2) {   // PS2 sub-plane NHWC16 [b][sub][H][W][OCALL/4]
        __bf16* outp = (__bf16*)outv;
        const int HW = H * W;
        const int CP = OCALL >> 2;
#pragma unroll
        for (int m = 0; m < MT; m++) {
            int cc = (ocb + m * 16 + kg * 4) >> 2;   // channel in sub-plane
#pragma unroll
            for (int n = 0; n < 4; n++) {
                int pix = (h0 + row0 + n) * W + w0 + cl;
#pragma unroll
                for (int j = 0; j < 4; j++) {        // j == subpixel index
                    float f = acc[m][n][j];
                    if (RELU_OUT) f = fmaxf(f, 0.f);
                    outp[((size_t)(b * 4 + j) * HW + pix) * CP + cc] = (__bf16)f;
                }
            }
        }
    } else {   // OUTM == 3: PS2 FULL NHWC [b][2H][2W][OCALL/4]
        __bf16* outp = (__bf16*)outv;
        const int CP = OCALL >> 2;
        const int H2 = 2 * H, W2 = 2 * W;
#pragma unroll
        for (int m = 0; m < MT; m++) {
            int cc = (ocb + m * 16 + kg * 4) >> 2;
#pragma unroll
            for (int n = 0; n < 4; n++) {
                int hh = h0 + row0 + n, ww = w0 + cl;
#pragma unroll
                for (int j = 0; j < 4; j++) {
                    // oc = cc*4 + a*2 + bb -> HR pixel (2h+a, 2w+bb)
                    int a = (j >> 1) & 1, bb = j & 1;
                    float f = acc[m][n][j];
                    if (RELU_OUT) f = fmaxf(f, 0.f);
                    outp[(((size_t)(b * H2 + 2 * hh + a)) * W2 + (2 * ww + bb)) * CP + cc]
                        = (__bf16)f;
                }
            }
        }
    }
}

// ===========================================================================
// r_w3: 16->3 conv @512^2 from PS2 sub-plane NHWC16 r2 [b][4][256][256][16].
// ===========================================================================
__global__ __launch_bounds__(256) void rw3_k(
    const __bf16* __restrict__ r2p, const float* __restrict__ w,
    const float* __restrict__ bias, float* __restrict__ E)
{
    const int tid = threadIdx.x;
    const int tY = (blockIdx.x >> 4) * 16;
    const int tX = (blockIdx.x & 15) * 16;
    const int b = blockIdx.y;

    __shared__ __bf16 xs[4][18][18][16];   // [sub][y][x][ch]
    __shared__ float wl[3][9][16];
    for (int i = tid; i < 432; i += 256) {
        int oc = i / 144, r = i - oc * 144;
        int t = r >> 4, e = r & 15;
        wl[oc][t][e] = w[(oc * 16 + e) * 9 + t];
    }
    for (int i = tid; i < 4 * 18 * 36; i += 256) {
        int g = i % 36; int r = i / 36;
        int y = r % 18, sub = r / 18;
        int px = g >> 1, half = g & 1;
        int gy = tY + y - 1, gx = tX + px - 1;
        uint4 v = make_uint4(0u, 0u, 0u, 0u);
        if (gy >= 0 && gy < 256 && gx >= 0 && gx < 256)
            v = *(const uint4*)(r2p
                + (((size_t)(b * 4 + sub) << 16) + (gy << 8) + gx) * 16 + half * 8);
        *(uint4*)(&xs[sub][y][px][half * 8]) = v;
    }
    __syncthreads();

    const int hyl = tid >> 3;           // 0..31
    const int hx0 = (tid & 7) * 4;      // 0..28
    float acc[3][4];
#pragma unroll
    for (int oc = 0; oc < 3; oc++)
#pragma unroll
        for (int p = 0; p < 4; p++) acc[oc][p] = bias[oc];

#pragma unroll
    for (int dy = 0; dy < 3; dy++) {
        int hy = hyl + dy - 1;
        int ys = (hy >> 1) + 1;
        int suby = (hy & 1) << 1;
#pragma unroll
        for (int dx = 0; dx < 3; dx++) {
            const int t = dy * 3 + dx;
#pragma unroll
            for (int p = 0; p < 4; p++) {
                int hx = hx0 + p + dx - 1;
                int sub = suby | (hx & 1);
                int xsx = (hx >> 1) + 1;
                const __bf16* bp = &xs[sub][ys][xsx][0];
                bf16x8 v0 = *(const bf16x8*)bp;
                bf16x8 v1 = *(const bf16x8*)(bp + 8);
#pragma unroll
                for (int e = 0; e < 8; e++) {
                    float f0 = (float)v0[e], f1 = (float)v1[e];
                    acc[0][p] = fmaf(f0, wl[0][t][e], acc[0][p]);
                    acc[1][p] = fmaf(f0, wl[1][t][e], acc[1][p]);
                    acc[2][p] = fmaf(f0, wl[2][t][e], acc[2][p]);
                    acc[0][p] = fmaf(f1, wl[0][t][e + 8], acc[0][p]);
                    acc[1][p] = fmaf(f1, wl[1][t][e + 8], acc[1][p]);
                    acc[2][p] = fmaf(f1, wl[2][t][e + 8], acc[2][p]);
                }
            }
        }
    }
    const int HY = tY * 2 + hyl, HX = tX * 2 + hx0;
#pragma unroll
    for (int oc = 0; oc < 3; oc++) {
        float4 v = make_float4(acc[oc][0], acc[oc][1], acc[oc][2], acc[oc][3]);
        *(float4*)&E[(((size_t)(b * 3 + oc)) << 18) + HY * 512 + HX] = v;
    }
}

// ===========================================================================
// filter: normalize + dynamic 5x5 + PS4 + residual. Ut NHWC [b][16384][400].
// ===========================================================================
__global__ __launch_bounds__(256) void filter_k(
    const __bf16* __restrict__ Ut, const float* __restrict__ x,
    const float* __restrict__ E, float* __restrict__ out)
{
    const int tid = threadIdx.x;
    const int s  = tid >> 4;    // subpixel 0..15
    const int pl = tid & 15;    // pixel lane
    const int b  = blockIdx.y;
    const int pix0 = blockIdx.x * 16;
    const int y  = pix0 >> 7;
    const int x0 = pix0 & 127;

    __shared__ float xp[3][5][20];
    __shared__ float vs[3][16][16];    // [c][s][pl]
    __shared__ __bf16 ut[16][408];     // [px][ch], padded row

    for (int i = tid; i < 800; i += 256) {         // 16 px x 50 groups of 8
        int px = i / 50, g = i - px * 50;
        uint4 v = *(const uint4*)(Ut + ((size_t)(b * 16384 + pix0 + px) * 400 + g * 8));
        *(uint4*)(&ut[px][g * 8]) = v;
    }
    for (int i = tid; i < 300; i += 256) {
        int c = i / 100, r = i - c * 100;
        int dy = r / 20, dx = r - dy * 20;
        int gy = y + dy - 2, gx = x0 + dx - 2;
        float v = 0.f;
        if (gy >= 0 && gy < 128 && gx >= 0 && gx < 128)
            v = x[((size_t)(b * 3 + c) * 128 + gy) * 128 + gx];
        xp[c][dy][dx] = v;
    }
    __syncthreads();

    float u[25], m = 0.f;
#pragma unroll
    for (int tap = 0; tap < 25; tap++) {
        u[tap] = (float)ut[pl][tap * 16 + s];
        m += u[tap];
    }
    m *= 0.04f;
#pragma unroll
    for (int c = 0; c < 3; c++) {
        float a = 0.f;
#pragma unroll
        for (int tap = 0; tap < 25; tap++)
            a = fmaf(xp[c][tap / 5][pl + tap % 5], u[tap] - m + 0.04f, a);
        vs[c][s][pl] = a;
    }
    __syncthreads();

    const size_t Eb = (size_t)b * 3 * 262144;
    for (int i = tid; i < 768; i += 256) {
        int c = i >> 8, r = i & 255;
        int s1 = r >> 6, cc = r & 63;
        float v = vs[c][s1 * 4 + (cc & 3)][cc >> 2];
        size_t o = Eb + (size_t)c * 262144 + (size_t)(y * 4 + s1) * 512 + x0 * 4 + cc;
        out[o] = v + E[o];
    }
}

// ===========================================================================
extern "C" void kernel_launch(void* const* d_in, const int* in_sizes, int n_in,
                              void* d_out, int out_size, void* d_ws, size_t ws_size,
                              hipStream_t stream)
{
    const float* x      = (const float*)d_in[0];
    const float* w_in   = (const float*)d_in[1];
    const float* b_in   = (const float*)d_in[2];
    const float* res_w1 = (const float*)d_in[3];
    const float* res_b1 = (const float*)d_in[4];
    const float* res_w2 = (const float*)d_in[5];
    const float* res_b2 = (const float*)d_in[6];
    const float* r_w1   = (const float*)d_in[7];
    const float* r_b1   = (const float*)d_in[8];
    const float* r_w2   = (const float*)d_in[9];
    const float* r_b2   = (const float*)d_in[10];
    const float* r_w3   = (const float*)d_in[11];
    const float* r_b3   = (const float*)d_in[12];
    const float* k_w1   = (const float*)d_in[13];
    const float* k_b1   = (const float*)d_in[14];
    const float* k_w2   = (const float*)d_in[15];
    const float* k_b2   = (const float*)d_in[16];
    float* out = (float*)d_out;

    char* ws = (char*)d_ws;
    __bf16* WT = (__bf16*)ws;                   // pre-swizzled weights, 3.06 MB
    __bf16* ZP = (__bf16*)(ws + 3110912);       // 256B zeros page
    __bf16* F  = (__bf16*)(ws + 3145728);       // [4,128,128,64]   8.4 MB
    __bf16* Hb = (__bf16*)(ws + 11534336);      // [4,128,128,64]   8.4 MB
    __bf16* R1 = (__bf16*)(ws + 19922944);      // PS2-full NHWC32 [4,256,256,32]
    __bf16* R2 = (__bf16*)(ws + 36700160);      // [4][4][256][256][16] 33.6 MB
    __bf16* K1 = (__bf16*)(ws + 70254592);      // [4,128,128,128] 16.8 MB
    float*  E  = (float*) (ws + 87031808);      // [4,3,512,512]   12.6 MB
    __bf16* Ut = (__bf16*)(ws + 3145728);       // [4][16384][400] 52.4 MB (overlay)

    // WT offsets (bf16 elems); kw2 padded to 416 ocs = 479232 elems
    const int oRes1 = 0, oRes2 = 442368, oRw1 = 884736, oKw1 = 958464,
              oRw2 = 1032192, oKw2 = 1050624;   // end 1529856 < cap

    WTab tab;
    for (int i = 0; i < 12; i++)
        tab.s[i]      = { res_w1 + (size_t)i * 36864, oRes1 + i * 36864, 64, 64, 64, 64 };
    for (int i = 0; i < 12; i++)
        tab.s[12 + i] = { res_w2 + (size_t)i * 36864, oRes2 + i * 36864, 64, 64, 64, 64 };
    tab.s[24] = { r_w1, oRw1, 128, 128, 64, 64 };
    tab.s[25] = { k_w1, oKw1, 128, 128, 64, 64 };
    tab.s[26] = { r_w2, oRw2, 64, 64, 32, 32 };
    tab.s[27] = { k_w2, oKw2, 400, 416, 128, 32 };

    dim3 blk(256);
    hipMemsetAsync(ZP, 0, 256, stream);
    // 288 blocks covers segs 0..26 (max n = 128*64*9 = 73728 = 288*256)
    wcvt_k<<<dim3(288, 27), blk, 0, stream>>>(tab, WT, 0);
    // kw2 padded: 416*128*9 = 479232 = 1872*256
    wcvt_k<<<dim3(1872, 1), blk, 0, stream>>>(tab, WT, 27);

    conv_in_k<<<dim3(64, 4), blk, 0, stream>>>(x, w_in, b_in, F);

    // 12 residual blocks — ICB=64 single-chunk (one barrier pair per block)
    for (int i = 0; i < 12; i++) {
        convm_k<64, 64, 2, 0, 0, true, true, false, false>
            <<<dim3(64, 4, 2), blk, 0, stream>>>(
            F, WT + oRes1 + i * 36864, res_b1 + i * 64, Hb, ZP, 128, 128, 64, 0);
        convm_k<64, 64, 2, 2, 0, false, false, true, false>
            <<<dim3(64, 4, 2), blk, 0, stream>>>(
            Hb, WT + oRes2 + i * 36864, res_b2 + i * 64, F, ZP, 128, 128, 64, 0);
    }

    // residual branch: r_w1 -> R1 (PS2 FULL NHWC32 @256^2, ReLU'd)
    convm_k<64, 64, 2, 0, 3, true, true, false, false>
        <<<dim3(64, 4, 4), blk, 0, stream>>>(
        F, WT + oRw1, r_b1, R1, ZP, 128, 128, 128, 0);
    // r_w2: plain NHWC32 conv @256^2, zero-VALU STAGE-2 staging
    convm_k<32, 32, 2, 2, 2, false, true, false, false>
        <<<dim3(256, 4, 2), blk, 0, stream>>>(
        R1, WT + oRw2, r_b2, R2, ZP, 256, 256, 64, 0);
    rw3_k<<<dim3(256, 4), blk, 0, stream>>>(R2, r_w3, r_b3, E);

    // kernel branch stem: k1 = relu(conv(relu(f)))
    convm_k<64, 64, 2, 0, 0, true, true, false, false>
        <<<dim3(64, 4, 4), blk, 0, stream>>>(
        F, WT + oKw1, k_b1, K1, ZP, 128, 128, 128, 0);

    // up-kernel GEMM -> Ut NHWC [b][16384][400] (13 z-blocks of 32, guarded;
    // stays at ICB=32: its 4-blk/CU occupancy config is the proven best)
    convm_k<128, 32, 2, 2, 0, false, false, false, true>
        <<<dim3(64, 4, 13), blk, 0, stream>>>(
        K1, WT + oKw2, k_b2, Ut, ZP, 128, 128, 400, 0);

    // normalize + dynamic filter + PS4 + residual
    filter_k<<<dim3(1024, 4), blk, 0, stream>>>(Ut, x, E, out);
}